// Round 8
// baseline (120.958 us; speedup 1.0000x reference)
//
#include <hip/hip_runtime.h>
#include <stdint.h>

// B=2,H=16 -> BH=32; S=2048, D=64. chunk_size telescopes out:
// out = causal attention with phi(s)=s+0.5*s^2, s=(q*D^-0.5).k
#define SEQ  2048
#define DH   64
#define BH_N 32
#define SCALE 0.125f

typedef __attribute__((ext_vector_type(8))) short short8;   // 8 bf16
typedef __attribute__((ext_vector_type(4))) float f32x4;    // MFMA C/D

static __device__ __forceinline__ unsigned short f2bf(float f) {
  unsigned int u = __float_as_uint(f);
  u += 0x7fffu + ((u >> 16) & 1u);   // RNE
  return (unsigned short)(u >> 16);
}
// HW packed f32->bf16 (RNE), 1 instr per pair: d.lo=bf16(a), d.hi=bf16(b)
static __device__ __forceinline__ unsigned cvtpk(float a, float b) {
  unsigned r;
  asm("v_cvt_pk_bf16_f32 %0, %1, %2" : "=v"(r) : "v"(a), "v"(b));
  return r;
}

typedef __attribute__((address_space(1))) const unsigned char* gp1;
typedef __attribute__((address_space(3))) unsigned char* lp3;
static __device__ __forceinline__ void stage16(const void* g, void* l) {
  __builtin_amdgcn_global_load_lds((gp1)g, (lp3)l, 16, 0, 0);
}

// ---------------------------------------------------------------------------
// Prep: per (bh, 64-key tile) produce 16B-unit-packed tiles (512 units/tile).
// KEY PERMUTATION: tile row position pos(k) = (k&32)|((k&4)<<2)|((k&24)>>1)|(k&3)
// (inverse: actual key at pos n*16+row = 32*(n>>1)+(row>>2)*8+(n&1)*4+(row&3)).
// With this order, the two QK sub-tile outputs nt=2a,2a+1 leave lane (quad,low)
// holding S^T for actual keys a*32+quad*8+{0..7} == a 16x16x32 B-fragment, so
// PV runs as full-K mfma_f32_16x16x32_bf16 with no operand shuffles.
//  kb2 unit u = c*64+pos (c=ks*4+quad): shorts j = K[key][ks*32+quad*8+j] (bf16)
//  vt2 unit u = a*256+ft*64+quad*16+low: shorts j = V[a*32+quad*8+j][ft*16+low]
// ---------------------------------------------------------------------------
__global__ __launch_bounds__(256) void prep_kernel(
    const float* __restrict__ kin, const float* __restrict__ vin,
    unsigned short* __restrict__ kb2, unsigned short* __restrict__ vt2)
{
  const int sb = blockIdx.x;    // 0..31 (64 keys each)
  const int bh = blockIdx.y;    // 0..31
  const int t  = threadIdx.x;   // 0..255
  __shared__ __align__(16) unsigned short lds[4096];
  const size_t base  = ((size_t)bh * SEQ + (size_t)sb * 64) * DH;
  const size_t obase = ((size_t)bh * 32 + sb) * 4096;   // shorts per tile

  // ---- K ----
  #pragma unroll
  for (int i = 0; i < 4; ++i) {
    int idx = i * 256 + t, key = idx >> 4, F = (idx & 15) * 4;
    float4 f = *reinterpret_cast<const float4*>(kin + base + key * DH + F);
    int pos = (key & 32) | ((key & 4) << 2) | ((key & 24) >> 1) | (key & 3);
    int c = (F >> 5) * 4 + ((F >> 3) & 3), jh = (F >> 2) & 1;
    uint2 pk; pk.x = cvtpk(f.x, f.y); pk.y = cvtpk(f.z, f.w);
    *reinterpret_cast<uint2*>(lds + (c * 64 + pos) * 8 + jh * 4) = pk;
  }
  __syncthreads();
  #pragma unroll
  for (int uu = 0; uu < 2; ++uu) {
    int u = uu * 256 + t;
    *reinterpret_cast<uint4*>(kb2 + obase + u * 8) =
        *reinterpret_cast<const uint4*>(lds + u * 8);
  }
  __syncthreads();
  // ---- V ----
  #pragma unroll
  for (int i = 0; i < 4; ++i) {
    int idx = i * 256 + t, key = idx >> 4, F = (idx & 15) * 4;
    float4 f = *reinterpret_cast<const float4*>(vin + base + key * DH + F);
    int a = key >> 5, qd = (key >> 3) & 3, jj = key & 7;
    int u0 = a * 256 + (F >> 4) * 64 + qd * 16 + (F & 15);
    lds[(u0 + 0) * 8 + jj] = f2bf(f.x);
    lds[(u0 + 1) * 8 + jj] = f2bf(f.y);
    lds[(u0 + 2) * 8 + jj] = f2bf(f.z);
    lds[(u0 + 3) * 8 + jj] = f2bf(f.w);
  }
  __syncthreads();
  #pragma unroll
  for (int uu = 0; uu < 2; ++uu) {
    int u = uu * 256 + t;
    *reinterpret_cast<uint4*>(vt2 + obase + u * 8) =
        *reinterpret_cast<const uint4*>(lds + u * 8);
  }
}

// ---------------------------------------------------------------------------
// attn: grid (16,32), 256 threads (4 waves). XCD-aware remap (bijective,
// 512 = 64 x 8): XCD c owns bh in {4c..4c+3}; KV is L2-resident (PMC: FETCH
// ~= q only).
//
// R7 (all-register) was VMEM-return-BW bound: every wave pulled the full
// 16KB K+V tile into registers (128KB/CU/slot through the 64B/cyc return
// path; rh-pair redundancy unavoidable at reg level). This version stages
// each tile ONCE per block into a DEPTH-4 LDS RING with stage-2-ahead,
// counted vmcnt(8), and ONE barrier per slot (T3/T4):
//   iter s: STAGE(s+2 -> buf[(s+2)&3]); s_waitcnt vmcnt(8); s_barrier;
//           COMPUTE(s) from buf[s&3].
// Ring safety: a wave issuing STAGE(s+2) can only coexist with waves
// computing slot s-1 or s (collective barrier) -> target buffer differs by
// 2 or 3 mod 4 from any reader. vmcnt(8) = stages for s+1,s+2 in flight;
// slot-s loads (3rd newest batch) are guaranteed landed before the barrier.
//
// All 4 waves work the SAME slot, split by rh=w&1 (32 q-rows) x ag=w>>1
// (32-key group): 16 MFMA + 8 ds_read_b128 per wave per slot. Staging role:
// wave w stages half (w&1) of (w>>1 ? V : K): 4 stage16 each.
// Split-K over ag merged via LDS reuse at the end.
// S^T = K.Q^T (16x16x32, key-permuted rows) -> phi in-register -> cvt_pk to
// K=32 P^T B-frags -> O^T += V^T.P^T (16x16x32).
// ---------------------------------------------------------------------------
__global__ __launch_bounds__(256, 2) void attn_kernel(
    const float* __restrict__ q,
    const unsigned short* __restrict__ kb2,
    const unsigned short* __restrict__ vt2,
    float* __restrict__ out)
{
  const int lid  = blockIdx.y * 16 + blockIdx.x;   // hw dispatch order
  const int xcd  = lid & 7;
  const int jj_  = lid >> 3;                       // 0..63
  const int bh   = (xcd << 2) | (jj_ >> 4);        // 4 bh per XCD
  const int qa   = jj_ & 15;
  const int tid  = threadIdx.x;
  const int w    = tid >> 6;          // 0..3
  const int lane = tid & 63;
  const int low  = lane & 15;
  const int quad = lane >> 4;
  const int rh   = w & 1;             // q-row half
  const int ag   = w >> 1;            // key 32-group
  const int nB   = 32 - qa;           // number of B-steps (>=17, so slots 0,1 are B)

  // depth-4 ring: K tiles 4x8KB + V tiles 4x8KB = 64KB
  __shared__ __align__(16) unsigned short klsAll[4 * 4096];
  __shared__ __align__(16) unsigned short vlsAll[4 * 4096];

  const unsigned short* kb_h = kb2 + (size_t)bh * 32 * 4096;
  const unsigned short* v2_h = vt2 + (size_t)bh * 32 * 4096;

  // Q B-frags for both tiles (scaled bf16), registers for whole kernel
  short8 aqA[2][2], aqB[2][2];
  #pragma unroll
  for (int tsel = 0; tsel < 2; ++tsel) {
    const int qt = tsel ? (31 - qa) : qa;
    #pragma unroll
    for (int h = 0; h < 2; ++h) {
      const float* qp =
          q + ((size_t)bh * SEQ + qt * 64 + rh * 32 + h * 16 + low) * DH + quad * 8;
      #pragma unroll
      for (int ks = 0; ks < 2; ++ks) {
        float4 f0 = *reinterpret_cast<const float4*>(qp + ks * 32);
        float4 f1 = *reinterpret_cast<const float4*>(qp + ks * 32 + 4);
        uint4 uv;
        uv.x = cvtpk(f0.x * SCALE, f0.y * SCALE);
        uv.y = cvtpk(f0.z * SCALE, f0.w * SCALE);
        uv.z = cvtpk(f1.x * SCALE, f1.y * SCALE);
        uv.w = cvtpk(f1.z * SCALE, f1.w * SCALE);
        short8 a = __builtin_bit_cast(short8, uv);
        if (tsel) aqB[h][ks] = a; else aqA[h][ks] = a;
      }
    }
  }

  f32x4 oaccA[2][4], oaccB[2][4];
  #pragma unroll
  for (int h = 0; h < 2; ++h)
    #pragma unroll
    for (int i = 0; i < 4; ++i) {
      oaccA[h][i] = (f32x4){0.f, 0.f, 0.f, 0.f};
      oaccB[h][i] = (f32x4){0.f, 0.f, 0.f, 0.f};
    }

  // staging role: waves 0,1 -> K halves 0,1; waves 2,3 -> V halves 0,1
  const int stV   = w >> 1;
  const int half_ = w & 1;
  const unsigned short* gsrc = stV ? v2_h : kb_h;
  unsigned short* ldsb = stV ? vlsAll : klsAll;

  #define STAGE(T, BUF)                                                        \
    do {                                                                       \
      const unsigned short* gs_ = gsrc + (size_t)(T) * 4096;                   \
      unsigned short* ld_ = ldsb + (BUF) * 4096;                               \
      _Pragma("unroll")                                                        \
      for (int r_ = 0; r_ < 4; ++r_) {                                         \
        const int u_ = (half_ * 4 + r_) * 64 + lane;                           \
        stage16(gs_ + u_ * 8, ld_ + u_ * 8);                                   \
      }                                                                        \
    } while (0)

  // Wave's 32-key group ag: QK^T over two permuted 16-row sub-tiles leaves
  // lane holding S^T for actual keys ag*32+quad*8+{0..7}; phi + cvt_pk builds
  // the K=32 P^T B-fragment; PV is 4 full-K MFMAs per h.
  #define COMPUTE(AQ, OACC)                                                    \
    do {                                                                       \
      short8 vfr[4], kfr[4];                                                   \
      _Pragma("unroll")                                                        \
      for (int ft = 0; ft < 4; ++ft)                                           \
        vfr[ft] = *reinterpret_cast<const short8*>(                            \
            vT + ((ag * 4 + ft) * 64 + lane) * 8);                             \
      _Pragma("unroll")                                                        \
      for (int ks = 0; ks < 2; ++ks)                                           \
        _Pragma("unroll")                                                      \
        for (int sub = 0; sub < 2; ++sub)                                      \
          kfr[ks * 2 + sub] = *reinterpret_cast<const short8*>(                \
              kT + ((ks * 4 + quad) * 64 + (ag * 2 + sub) * 16 + low) * 8);    \
      f32x4 s00 = (f32x4){0.f, 0.f, 0.f, 0.f};                                 \
      f32x4 s01 = s00, s10 = s00, s11 = s00;                                   \
      __builtin_amdgcn_s_setprio(1);                                           \
      _Pragma("unroll")                                                        \
      for (int ks = 0; ks < 2; ++ks) {                                         \
        s00 = __builtin_amdgcn_mfma_f32_16x16x32_bf16(                         \
            kfr[ks * 2 + 0], AQ[0][ks], s00, 0, 0, 0);                         \
        s01 = __builtin_amdgcn_mfma_f32_16x16x32_bf16(                         \
            kfr[ks * 2 + 0], AQ[1][ks], s01, 0, 0, 0);                         \
        s10 = __builtin_amdgcn_mfma_f32_16x16x32_bf16(                         \
            kfr[ks * 2 + 1], AQ[0][ks], s10, 0, 0, 0);                         \
        s11 = __builtin_amdgcn_mfma_f32_16x16x32_bf16(                         \
            kfr[ks * 2 + 1], AQ[1][ks], s11, 0, 0, 0);                         \
      }                                                                        \
      _Pragma("unroll")                                                        \
      for (int h = 0; h < 2; ++h) {                                            \
        f32x4 sA = h ? s01 : s00; /* keys ag*32+quad*8+r   */                  \
        f32x4 sB = h ? s11 : s10; /* keys ag*32+quad*8+4+r */                  \
        float pv[8];                                                           \
        _Pragma("unroll")                                                      \
        for (int r = 0; r < 4; ++r) {                                          \
          float x0 = sA[r], x1 = sB[r];                                        \
          pv[r]     = __builtin_fmaf(0.5f * x0, x0, x0);                       \
          pv[4 + r] = __builtin_fmaf(0.5f * x1, x1, x1);                       \
        }                                                                      \
        if (diag) {                                                            \
          const int qrow = rh * 32 + h * 16 + low;                             \
          _Pragma("unroll")                                                    \
          for (int r = 0; r < 4; ++r) {                                        \
            if ((ag * 32 + quad * 8 + r) > qrow)     pv[r]     = 0.f;          \
            if ((ag * 32 + quad * 8 + 4 + r) > qrow) pv[4 + r] = 0.f;          \
          }                                                                    \
        }                                                                      \
        uint4 uu;                                                              \
        uu.x = cvtpk(pv[0], pv[1]); uu.y = cvtpk(pv[2], pv[3]);                \
        uu.z = cvtpk(pv[4], pv[5]); uu.w = cvtpk(pv[6], pv[7]);                \
        short8 pf = __builtin_bit_cast(short8, uu);                            \
        _Pragma("unroll")                                                      \
        for (int ft = 0; ft < 4; ++ft)                                         \
          OACC[h][ft] = __builtin_amdgcn_mfma_f32_16x16x32_bf16(               \
              vfr[ft], pf, OACC[h][ft], 0, 0, 0);                             \
      }                                                                        \
      __builtin_amdgcn_s_setprio(0);                                           \
    } while (0)

  // Prologue: stage slots 0 and 1 (both < nB always, since nB >= 17).
  STAGE(0, 0);
  STAGE(1, 1);

  for (int s = 0; s <= 32; ++s) {
    int sp = s + 2; if (sp > 32) sp = 32;            // clamped re-stage, harmless
    const int Tp = (sp < nB) ? sp : (sp - nB);
    STAGE(Tp, (s + 2) & 3);
    asm volatile("s_waitcnt vmcnt(8)" ::: "memory"); // own slot-s loads landed
    __builtin_amdgcn_s_barrier();                    // everyone's slot-s landed
    asm volatile("" ::: "memory");

    const int buf = s & 3;
    const unsigned short* kT = klsAll + buf * 4096;
    const unsigned short* vT = vlsAll + buf * 4096;
    const bool diag = (s == nB - 1) || (s == 32);
    if (s >= nB) COMPUTE(aqA, oaccA);
    else         COMPUTE(aqB, oaccB);
  }

  // ---- split-K merge over ag via LDS (reuse klsAll: 32KB) + epilogue ----
  __syncthreads();
  float* mls = reinterpret_cast<float*>(&klsAll[0]);
  float* mw  = mls + rh * 4096;
  if (ag == 1) {
    #pragma unroll
    for (int h = 0; h < 2; ++h)
      #pragma unroll
      for (int ft = 0; ft < 4; ++ft) {
        *reinterpret_cast<f32x4*>(mw + ((0 * 8 + h * 4 + ft) * 256 + lane * 4)) =
            oaccA[h][ft];
        *reinterpret_cast<f32x4*>(mw + ((1 * 8 + h * 4 + ft) * 256 + lane * 4)) =
            oaccB[h][ft];
      }
  }
  __syncthreads();
  if (ag == 0) {
    #pragma unroll
    for (int tsel = 0; tsel < 2; ++tsel) {
      const int qt = tsel ? (31 - qa) : qa;
      #pragma unroll
      for (int h = 0; h < 2; ++h)
        #pragma unroll
        for (int ft = 0; ft < 4; ++ft) {
          f32x4 o = tsel ? oaccB[h][ft] : oaccA[h][ft];
          f32x4 m = *reinterpret_cast<const f32x4*>(
              mw + ((tsel * 8 + h * 4 + ft) * 256 + lane * 4));
          o += m;
          *reinterpret_cast<f32x4*>(
              out + ((size_t)bh * SEQ + qt * 64 + rh * 32 + h * 16 + low) * DH +
              ft * 16 + quad * 4) = o;
        }
    }
  }
}

extern "C" void kernel_launch(void* const* d_in, const int* in_sizes, int n_in,
                              void* d_out, int out_size, void* d_ws, size_t ws_size,
                              hipStream_t stream)
{
  const float* q = (const float*)d_in[0];
  const float* k = (const float*)d_in[1];
  const float* v = (const float*)d_in[2];
  float* out = (float*)d_out;

  unsigned short* kb2 = (unsigned short*)d_ws;             // 8.4 MB bf16 packed
  unsigned short* vt2 = kb2 + (size_t)BH_N * SEQ * DH;     // 8.4 MB bf16 packed

  prep_kernel<<<dim3(32, BH_N), 256, 0, stream>>>(k, v, kb2, vt2);
  attn_kernel<<<dim3(16, BH_N), 256, 0, stream>>>(q, kb2, vt2, out);
}